// Round 17
// baseline (189.287 us; speedup 1.0000x reference)
//
#include <hip/hip_runtime.h>
#include <cmath>

#define Bz 32
#define Nz 512
#define Dz 1024
#define Hz 8
#define DHz 64
#define INNERz 512
#define PROJz 512
#define MIDz 768
#define EPSz 1e-5f

typedef unsigned short u16;
typedef unsigned int u32;
typedef __attribute__((ext_vector_type(8))) short short8v;
typedef __attribute__((ext_vector_type(8))) unsigned short ushort8v;
typedef __attribute__((ext_vector_type(4))) unsigned short ushort4v;
typedef __attribute__((ext_vector_type(4))) unsigned int uint4v;
typedef __attribute__((ext_vector_type(4))) float f32x4;

__device__ __forceinline__ u16 f2bf(float x) {  // RNE f32 -> bf16 (finite inputs)
  unsigned u = __float_as_uint(x);
  unsigned r = u + 0x7fff + ((u >> 16) & 1);
  return (u16)(r >> 16);
}
__device__ __forceinline__ float bf2f(u16 u) {
  return __uint_as_float(((unsigned)u) << 16);
}
__device__ __forceinline__ float fexp2(float x) {  // 2^x, single v_exp_f32
  float r;
  asm("v_exp_f32 %0, %1" : "=v"(r) : "v"(x));
  return r;
}
__device__ __forceinline__ u32 cvtpk(float lo, float hi) {  // packed bf16(lo)|bf16(hi)<<16
  u32 r;
  asm("v_cvt_pk_bf16_f32 %0, %1, %2" : "=v"(r) : "v"(lo), "v"(hi));
  return r;
}

// ---------- P0: weight prep. blocks 0..39: WkvTg/WqTg + colsums. blocks 40..551: Wout^T.
__global__ __launch_bounds__(256) void k_prepw(
    const float* __restrict__ Wkv, const float* __restrict__ Wq,
    const float* __restrict__ g_ctx, const float* __restrict__ g_q,
    u16* __restrict__ WkvTg, u16* __restrict__ WqTg,
    float* __restrict__ cskv4, float* __restrict__ csq4,
    const float* __restrict__ Wout, u16* __restrict__ WoutT) {
  __shared__ float part[64][4];
  __shared__ float sm[32][33];
  const int t = threadIdx.x;
  const int blk = blockIdx.x;
  if (blk >= 40) {  // Wout transpose: WoutT[n][k] = bf16(Wout[k][n])
    const int bid2 = blk - 40;
    const int n0 = (bid2 & 31) * 32, k0 = (bid2 >> 5) * 32;
    {
      const int kk = t >> 3, nn = (t & 7) * 4;
      const float4 v = *reinterpret_cast<const float4*>(Wout + (size_t)(k0 + kk) * Dz + n0 + nn);
      sm[kk][nn] = v.x; sm[kk][nn + 1] = v.y; sm[kk][nn + 2] = v.z; sm[kk][nn + 3] = v.w;
    }
    __syncthreads();
    const int nn = t >> 3, kk = (t & 7) * 4;
    ushort4v pk;
#pragma unroll
    for (int j = 0; j < 4; ++j) pk[j] = f2bf(sm[kk + j][nn]);
    *reinterpret_cast<ushort4v*>(WoutT + (size_t)(n0 + nn) * INNERz + k0 + kk) = pk;
    return;
  }
  const int jg = blk >> 2, quarter = blk & 3;
  const bool isq = jg >= 2;
  const int jbase = isq ? (jg - 2) * 64 : jg * 64;
  const int j = jbase + (t & 63);
  const int dsub = t >> 6;
  const float* W = isq ? Wq : Wkv;
  const int ld = isq ? 512 : 128;
  const float* g = isq ? g_q : g_ctx;
  const float scale = isq ? 0.125f * 1.4426950408889634f : 1.f;  // fold DH^-0.5 * log2e
  u16* WT = isq ? WqTg : WkvTg;
  float partial = 0.f;
  const int d0beg = quarter * 256 + dsub * 64;
  for (int d0 = d0beg; d0 < d0beg + 64; d0 += 2) {
    const float v0 = scale * g[d0] * W[(size_t)d0 * ld + j];
    const float v1 = scale * g[d0 + 1] * W[(size_t)(d0 + 1) * ld + j];
    partial += v0 + v1;
    *(u32*)(WT + (size_t)j * Dz + d0) = (u32)f2bf(v0) | ((u32)f2bf(v1) << 16);
  }
  part[t & 63][dsub] = partial;
  __syncthreads();
  if (t < 64)
    (isq ? csq4 : cskv4)[(jbase + t) * 4 + quarter] =
        part[t][0] + part[t][1] + part[t][2] + part[t][3];
}

#define LOADB2(dst, kk)                                                        \
  {                                                                            \
    _Pragma("unroll") for (int u_ = 0; u_ < 4; ++u_)                           \
    _Pragma("unroll") for (int cf_ = 0; cf_ < 2; ++cf_)                        \
        dst[u_][cf_] =                                                         \
            *(const short8v*)(Bp + (size_t)cf_ * 16 * Dz + (kk) + u_ * 32);    \
  }

// ---------- P1: qb = bf16( LN(queries)*g @ Wq * 0.125*log2e )  (reg-pipelined MFMA)
__global__ __launch_bounds__(256) void k_qproj(
    const float* __restrict__ queries, const u16* __restrict__ WT,
    const float* __restrict__ cs4, u16* __restrict__ qbuf) {
  __shared__ u16 hbuf[16 * 1024];
  __shared__ float mm[16], rr[16];
  char* hb = (char*)hbuf;
  const int t = threadIdx.x;
  const int w = t >> 6, l = t & 63;
  const int lr = l & 15, lk = l >> 4;
  const int c0 = blockIdx.y * 128 + w * 32;
  const u16* Bp = WT + (size_t)(c0 + lr) * Dz + lk * 8;
  short8v bcur[4][2], bnxt[4][2];
  LOADB2(bcur, 0);
  {
    const int r = t >> 4, c16 = t & 15;
    const long grow = (long)blockIdx.x * 16 + r;
    const float* xr = queries + grow * Dz;
    float s = 0.f, ss = 0.f;
    const int swz = (r & 7) << 4;
#pragma unroll
    for (int i = 0; i < 16; ++i) {
      const int col = c16 * 4 + i * 64;
      const float4 v = *(const float4*)(xr + col);
      s += (v.x + v.y) + (v.z + v.w);
      ss += (v.x * v.x + v.y * v.y) + (v.z * v.z + v.w * v.w);
      uint2 pk;
      pk.x = (u32)f2bf(v.x) | ((u32)f2bf(v.y) << 16);
      pk.y = (u32)f2bf(v.z) | ((u32)f2bf(v.w) << 16);
      *(uint2*)(hb + ((r * 2048 + col * 2) ^ swz)) = pk;
    }
#pragma unroll
    for (int off = 1; off <= 8; off <<= 1) { s += __shfl_xor(s, off); ss += __shfl_xor(ss, off); }
    const float mean = s * (1.f / Dz);
    const float rstd = rsqrtf(ss * (1.f / Dz) - mean * mean + EPSz);
    if (c16 == 0) { mm[r] = mean; rr[r] = rstd; }
  }
  __syncthreads();
  f32x4 acc[2];
  acc[0] = {0.f, 0.f, 0.f, 0.f};
  acc[1] = {0.f, 0.f, 0.f, 0.f};
  const int aswz = (lr & 7) << 4;
#pragma unroll
  for (int k0 = 0; k0 < Dz; k0 += 128) {
    if (k0 + 128 < Dz) LOADB2(bnxt, k0 + 128);
#pragma unroll
    for (int u = 0; u < 4; ++u) {
      const int kk = (k0 + u * 32 + lk * 8) * 2;
      const short8v a = *(const short8v*)(hb + ((lr * 2048 + kk) ^ aswz));
      acc[0] = __builtin_amdgcn_mfma_f32_16x16x32_bf16(a, bcur[u][0], acc[0], 0, 0, 0);
      acc[1] = __builtin_amdgcn_mfma_f32_16x16x32_bf16(a, bcur[u][1], acc[1], 0, 0, 0);
    }
    if (k0 + 128 < Dz) {
#pragma unroll
      for (int u = 0; u < 4; ++u) {
        bcur[u][0] = bnxt[u][0];
        bcur[u][1] = bnxt[u][1];
      }
    }
  }
  const long base = (long)blockIdx.x * 16;
#pragma unroll
  for (int cf = 0; cf < 2; ++cf) {
    const int col = c0 + cf * 16 + lr;
    const float c = cs4[col * 4] + cs4[col * 4 + 1] + cs4[col * 4 + 2] + cs4[col * 4 + 3];
#pragma unroll
    for (int q = 0; q < 4; ++q) {
      const int row = lk * 4 + q;
      qbuf[(size_t)(base + row) * INNERz + col] = f2bf(rr[row] * (acc[cf][q] - mm[row] * c));
    }
  }
}

// ---------- P2: k,v = LN(x+pos)*g @ Wkv — LDS-free, col-split for wave count.
// Block = 32 rows, 4 waves: wave (w>>1) row-group, (w&1) col-half (64 cols).
// 512 blocks -> 2048 waves -> 8 waves/CU. x read 2x (once per col-half wave).
__global__ __launch_bounds__(256) void k_ctxkv(
    const float* __restrict__ x, const float* __restrict__ pos,
    const u16* __restrict__ WT, const float* __restrict__ cs4,
    u16* __restrict__ kb, u16* __restrict__ vT) {
  const int t = threadIdx.x;
  const int w = t >> 6, l = t & 63;
  const int lr = l & 15, lk = l >> 4;
  const int colbase = (w & 1) * 64;
  const long rowbase = (long)blockIdx.x * 32 + (w >> 1) * 16;
  const int n0 = (int)(rowbase & (Nz - 1));
  const float* xr = x + (rowbase + lr) * Dz + lk * 8;
  const float* pr = pos + (size_t)(n0 + lr) * Dz + lk * 8;

  f32x4 acc[4];
#pragma unroll
  for (int cf = 0; cf < 4; ++cf) acc[cf] = {0.f, 0.f, 0.f, 0.f};
  float s = 0.f, ss = 0.f;

  for (int k0 = 0; k0 < Dz; k0 += 64) {
    float4 xv[4], pv[4];
    xv[0] = *(const float4*)(xr + k0);
    xv[1] = *(const float4*)(xr + k0 + 4);
    xv[2] = *(const float4*)(xr + k0 + 32);
    xv[3] = *(const float4*)(xr + k0 + 36);
    pv[0] = *(const float4*)(pr + k0);
    pv[1] = *(const float4*)(pr + k0 + 4);
    pv[2] = *(const float4*)(pr + k0 + 32);
    pv[3] = *(const float4*)(pr + k0 + 36);
    short8v afr[2];
#pragma unroll
    for (int sl = 0; sl < 2; ++sl) {
      float4 v0 = xv[sl * 2], v1 = xv[sl * 2 + 1];
      const float4 p0 = pv[sl * 2], p1 = pv[sl * 2 + 1];
      v0.x += p0.x; v0.y += p0.y; v0.z += p0.z; v0.w += p0.w;
      v1.x += p1.x; v1.y += p1.y; v1.z += p1.z; v1.w += p1.w;
      s += (v0.x + v0.y) + (v0.z + v0.w) + (v1.x + v1.y) + (v1.z + v1.w);
      ss += (v0.x * v0.x + v0.y * v0.y) + (v0.z * v0.z + v0.w * v0.w) +
            (v1.x * v1.x + v1.y * v1.y) + (v1.z * v1.z + v1.w * v1.w);
      uint4v pk;
      pk[0] = cvtpk(v0.x, v0.y);
      pk[1] = cvtpk(v0.z, v0.w);
      pk[2] = cvtpk(v1.x, v1.y);
      pk[3] = cvtpk(v1.z, v1.w);
      afr[sl] = *(short8v*)&pk;
    }
#pragma unroll
    for (int cf = 0; cf < 4; ++cf) {
      const u16* bp = WT + (size_t)(colbase + cf * 16 + lr) * Dz + lk * 8;
      const short8v b0 = *(const short8v*)(bp + k0);
      const short8v b1 = *(const short8v*)(bp + k0 + 32);
      acc[cf] = __builtin_amdgcn_mfma_f32_16x16x32_bf16(afr[0], b0, acc[cf], 0, 0, 0);
      acc[cf] = __builtin_amdgcn_mfma_f32_16x16x32_bf16(afr[1], b1, acc[cf], 0, 0, 0);
    }
  }
  // stats: lane covers row lr over its lk-quarter (full D); sum the 4 lk copies
  s += __shfl_xor(s, 16);
  s += __shfl_xor(s, 32);
  ss += __shfl_xor(ss, 16);
  ss += __shfl_xor(ss, 32);
  const float mean_l = s * (1.f / Dz);
  const float rstd_l = rsqrtf(ss * (1.f / Dz) - mean_l * mean_l + EPSz);
  float mnq[4], rsq[4];
#pragma unroll
  for (int q = 0; q < 4; ++q) {
    mnq[q] = __shfl(mean_l, lk * 4 + q, 64);
    rsq[q] = __shfl(rstd_l, lk * 4 + q, 64);
  }
  const int bb = (int)(rowbase >> 9);
#pragma unroll
  for (int cf = 0; cf < 4; ++cf) {
    const int col = colbase + cf * 16 + lr;
    const float c = cs4[col * 4] + cs4[col * 4 + 1] + cs4[col * 4 + 2] + cs4[col * 4 + 3];
    if (col < 64) {
#pragma unroll
      for (int q = 0; q < 4; ++q) {
        const long row = rowbase + lk * 4 + q;
        kb[(size_t)row * DHz + col] = f2bf(rsq[q] * (acc[cf][q] - mnq[q] * c));
      }
    } else {
      ushort4v pk;
#pragma unroll
      for (int q = 0; q < 4; ++q) pk[q] = f2bf(rsq[q] * (acc[cf][q] - mnq[q] * c));
      *(ushort4v*)(vT + ((size_t)bb * DHz + (col - 64)) * Nz + n0 + lk * 4) = pk;
    }
  }
}

// ---------- K3: MFMA flash attention. 4 waves/256 thr; 2 heads per wave; K/V staged 4x.
__global__ __launch_bounds__(256) void k_attn(
    const u16* __restrict__ qb, const u16* __restrict__ kb,
    const u16* __restrict__ vT, u16* __restrict__ ao) {
  __shared__ u16 Ks[2][4096];
  __shared__ u16 Vs[2][4096];
  __shared__ u16 plds[4][2048];   // per wave: 2 heads x (16x64) bf16
  const int t = threadIdx.x;
  const int w = t >> 6, l = t & 63;
  const int lr = l & 15, lk = l >> 4;
  const int m0 = blockIdx.x * 64 + w * 16;
  const int h0 = blockIdx.y * 2;
  const int b = blockIdx.z;
  const u16* qr = qb + (size_t)(m0 + lr) * INNERz + h0 * DHz + lk * 8;
  const short8v aq00 = *(const short8v*)qr;
  const short8v aq01 = *(const short8v*)(qr + 32);
  const short8v aq10 = *(const short8v*)(qr + 64);
  const short8v aq11 = *(const short8v*)(qr + 96);
  const u16* kbB = kb + (size_t)b * Nz * DHz;
  const u16* vTB = vT + (size_t)b * DHz * Nz;
  char* pw0 = (char*)&plds[w][0];
  char* pw1 = (char*)&plds[w][1024];
  const int swz = (lr & 7) << 4;

  const int srow = w * 16 + (l >> 3);
  const int schunk = (l & 7) ^ (l >> 3);

#define STAGE(bufi, j0v)                                                              \
  {                                                                                   \
    _Pragma("unroll") for (int c = 0; c < 2; ++c) {                                   \
      __builtin_amdgcn_global_load_lds(                                               \
          (const __attribute__((address_space(1))) u32*)(const void*)(                \
              kbB + (size_t)((j0v) + srow + c * 8) * DHz + schunk * 8),               \
          (__attribute__((address_space(3))) u32*)(void*)(&Ks[bufi][0] + w * 1024 + c * 512), \
          16, 0, 0);                                                                  \
      __builtin_amdgcn_global_load_lds(                                               \
          (const __attribute__((address_space(1))) u32*)(const void*)(                \
              vTB + (size_t)(srow + c * 8) * Nz + (j0v) + schunk * 8),                \
          (__attribute__((address_space(3))) u32*)(void*)(&Vs[bufi][0] + w * 1024 + c * 512), \
          16, 0, 0);                                                                  \
    }                                                                                 \
  }

  f32x4 oacc0[4], oacc1[4];
#pragma unroll
  for (int dn = 0; dn < 4; ++dn) { oacc0[dn] = {0.f, 0.f, 0.f, 0.f}; oacc1[dn] = {0.f, 0.f, 0.f, 0.f}; }
  float lsum0 = 0.f, lsum1 = 0.f;

  int buf = 0;
  STAGE(0, 0);
  asm volatile("s_waitcnt vmcnt(0)" ::: "memory");
  __builtin_amdgcn_s_barrier();
  asm volatile("" ::: "memory");

  for (int tt = 0; tt < 8; ++tt) {
    if (tt < 7) STAGE(buf ^ 1, (tt + 1) * 64);
    asm volatile("" ::: "memory");
    const char* Kb = (const char*)&Ks[buf][0];
    const char* Vb = (const char*)&Vs[buf][0];
    {
      f32x4 sfr[4];
#pragma unroll
      for (int jn = 0; jn < 4; ++jn) {
        const int rbase = jn * 2048 + lr * 128;
        const short8v bk0 = *(const short8v*)(Kb + rbase + ((lk * 16) ^ swz));
        const short8v bk1 = *(const short8v*)(Kb + rbase + ((64 + lk * 16) ^ swz));
        f32x4 c = {0.f, 0.f, 0.f, 0.f};
        c = __builtin_amdgcn_mfma_f32_16x16x32_bf16(bk0, aq00, c, 0, 0, 0);
        c = __builtin_amdgcn_mfma_f32_16x16x32_bf16(bk1, aq01, c, 0, 0, 0);
        sfr[jn] = c;
      }
      float ps = 0.f;
#pragma unroll
      for (int jn = 0; jn < 4; ++jn) {
        const float e0 = fexp2(sfr[jn][0]);
        const float e1 = fexp2(sfr[jn][1]);
        const float e2 = fexp2(sfr[jn][2]);
        const float e3 = fexp2(sfr[jn][3]);
        ps += (e0 + e1) + (e2 + e3);
        const int pbase = (lr * 128 + jn * 32 + lk * 8) ^ swz;
        *(u32*)(pw0 + pbase) = cvtpk(e0, e1);
        *(u32*)(pw0 + pbase + 4) = cvtpk(e2, e3);
      }
      lsum0 += ps;
    }
    {
      f32x4 sfr[4];
#pragma unroll
      for (int jn = 0; jn < 4; ++jn) {
        const int rbase = jn * 2048 + lr * 128;
        const short8v bk0 = *(const short8v*)(Kb + rbase + ((lk * 16) ^ swz));
        const short8v bk1 = *(const short8v*)(Kb + rbase + ((64 + lk * 16) ^ swz));
        f32x4 c = {0.f, 0.f, 0.f, 0.f};
        c = __builtin_amdgcn_mfma_f32_16x16x32_bf16(bk0, aq10, c, 0, 0, 0);
        c = __builtin_amdgcn_mfma_f32_16x16x32_bf16(bk1, aq11, c, 0, 0, 0);
        sfr[jn] = c;
      }
      float ps = 0.f;
#pragma unroll
      for (int jn = 0; jn < 4; ++jn) {
        const float e0 = fexp2(sfr[jn][0]);
        const float e1 = fexp2(sfr[jn][1]);
        const float e2 = fexp2(sfr[jn][2]);
        const float e3 = fexp2(sfr[jn][3]);
        ps += (e0 + e1) + (e2 + e3);
        const int pbase = (lr * 128 + jn * 32 + lk * 8) ^ swz;
        *(u32*)(pw1 + pbase) = cvtpk(e0, e1);
        *(u32*)(pw1 + pbase + 4) = cvtpk(e2, e3);
      }
      lsum1 += ps;
    }
    const short8v pa00 = *(const short8v*)(pw0 + ((lr * 128 + lk * 16) ^ swz));
    const short8v pa01 = *(const short8v*)(pw0 + ((lr * 128 + 64 + lk * 16) ^ swz));
    const short8v pa10 = *(const short8v*)(pw1 + ((lr * 128 + lk * 16) ^ swz));
    const short8v pa11 = *(const short8v*)(pw1 + ((lr * 128 + 64 + lk * 16) ^ swz));
#pragma unroll
    for (int dn = 0; dn < 4; ++dn) {
      const int rbase = dn * 2048 + lr * 128;
      const short8v bv0 = *(const short8v*)(Vb + rbase + ((lk * 16) ^ swz));
      const short8v bv1 = *(const short8v*)(Vb + rbase + ((64 + lk * 16) ^ swz));
      f32x4 o0 = oacc0[dn];
      o0 = __builtin_amdgcn_mfma_f32_16x16x32_bf16(pa00, bv0, o0, 0, 0, 0);
      o0 = __builtin_amdgcn_mfma_f32_16x16x32_bf16(pa01, bv1, o0, 0, 0, 0);
      oacc0[dn] = o0;
      f32x4 o1 = oacc1[dn];
      o1 = __builtin_amdgcn_mfma_f32_16x16x32_bf16(pa10, bv0, o1, 0, 0, 0);
      o1 = __builtin_amdgcn_mfma_f32_16x16x32_bf16(pa11, bv1, o1, 0, 0, 0);
      oacc1[dn] = o1;
    }
    asm volatile("" ::: "memory");
    if (tt < 7) asm volatile("s_waitcnt vmcnt(0)" ::: "memory");
    __builtin_amdgcn_s_barrier();
    asm volatile("" ::: "memory");
    buf ^= 1;
  }
#undef STAGE
  lsum0 += __shfl_xor(lsum0, 16);
  lsum0 += __shfl_xor(lsum0, 32);
  lsum1 += __shfl_xor(lsum1, 16);
  lsum1 += __shfl_xor(lsum1, 32);
  float rinv0[4], rinv1[4];
#pragma unroll
  for (int r = 0; r < 4; ++r) {
    rinv0[r] = 1.f / __shfl(lsum0, lk * 4 + r, 64);
    rinv1[r] = 1.f / __shfl(lsum1, lk * 4 + r, 64);
  }
#pragma unroll
  for (int dn = 0; dn < 4; ++dn)
#pragma unroll
    for (int r = 0; r < 4; ++r) {
      const int row = m0 + lk * 4 + r;
      const size_t rbase = ((size_t)b * Nz + row) * INNERz;
      ao[rbase + h0 * DHz + dn * 16 + lr] = f2bf(oacc0[dn][r] * rinv0[r]);
      ao[rbase + (h0 + 1) * DHz + dn * 16 + lr] = f2bf(oacc1[dn][r] * rinv1[r]);
    }
}

// ---------- K4a: out1 = bf16( ao @ Wout )  (128x128 tile, BK=64, XCD-swizzled grid)
__global__ __launch_bounds__(256) void k_wgemm(
    const u16* __restrict__ A, const u16* __restrict__ BT, u16* __restrict__ C) {
  __shared__ u16 As[128 * 64];
  __shared__ u16 Bs[128 * 64];
  const int t = threadIdx.x;
  const int w = t >> 6, l = t & 63;
  const int lin = blockIdx.y * gridDim.x + blockIdx.x;
  const int swzl = (lin & 7) * 128 + (lin >> 3);
  const int m0 = (swzl >> 3) * 128, n0 = (swzl & 7) * 128;
  const int wr = w >> 1, wc = w & 1;
  const int lr = l & 15, lk = l >> 4;

  f32x4 acc[4][4];
#pragma unroll
  for (int mt = 0; mt < 4; ++mt)
#pragma unroll
    for (int nt = 0; nt < 4; ++nt) acc[mt][nt] = {0.f, 0.f, 0.f, 0.f};

  for (int k0 = 0; k0 < INNERz; k0 += 64) {
#pragma unroll
    for (int c = 0; c < 4; ++c) {
      const int rowblk = w * 32 + c * 8;
      const int row = rowblk + (l >> 3);
      const int kb16 = (l & 7) * 8;
      __builtin_amdgcn_global_load_lds(
          (const __attribute__((address_space(1))) unsigned int*)(const void*)(
              A + (size_t)(m0 + row) * INNERz + k0 + kb16),
          (__attribute__((address_space(3))) unsigned int*)(void*)(As + rowblk * 64),
          16, 0, 0);
      __builtin_amdgcn_global_load_lds(
          (const __attribute__((address_space(1))) unsigned int*)(const void*)(
              BT + (size_t)(n0 + row) * INNERz + k0 + kb16),
          (__attribute__((address_space(3))) unsigned int*)(void*)(Bs + rowblk * 64),
          16, 0, 0);
    }
    __syncthreads();
#pragma unroll
    for (int ks = 0; ks < 2; ++ks) {
      short8v af[4], bf[4];
#pragma unroll
      for (int mt = 0; mt < 4; ++mt)
        af[mt] = *reinterpret_cast<const short8v*>(As + (wr * 64 + mt * 16 + lr) * 64 + ks * 32 + lk * 8);
#pragma unroll
      for (int nt = 0; nt < 4; ++nt)
        bf[nt] = *reinterpret_cast<const short8v*>(Bs + (wc * 64 + nt * 16 + lr) * 64 + ks * 32 + lk * 8);
#pragma unroll
      for (int mt = 0; mt < 4; ++mt)
#pragma unroll
        for (int nt = 0; nt < 4; ++nt)
          acc[mt][nt] = __builtin_amdgcn_mfma_f32_16x16x32_bf16(af[mt], bf[nt], acc[mt][nt], 0, 0, 0);
    }
    __syncthreads();
  }
#pragma unroll
  for (int mt = 0; mt < 4; ++mt)
#pragma unroll
    for (int nt = 0; nt < 4; ++nt) {
      const f32x4 a = acc[mt][nt];
#pragma unroll
      for (int r = 0; r < 4; ++r) {
        const size_t row = (size_t)m0 + wr * 64 + mt * 16 + lk * 4 + r;
        C[row * Dz + n0 + wc * 64 + nt * 16 + lr] = f2bf(a[r]);
      }
    }
}

// ---------- K4b: per-wave LN partial sums, 16 vals/lane, no spill, no atomics
__global__ __launch_bounds__(256) void k_lnmean(
    const u16* __restrict__ out1, float* __restrict__ pbuf) {
  const int t = threadIdx.x;
  const int w = t >> 6, l = t & 63;
  const long row0 = (long)blockIdx.x * 64 + w * 16;
  float acc[16];
#pragma unroll
  for (int j = 0; j < 16; ++j) acc[j] = 0.f;
  for (int rr = 0; rr < 16; ++rr) {
    const u16* rowp = out1 + (size_t)(row0 + rr) * Dz + l * 16;
    const ushort8v u0 = *(const ushort8v*)(rowp);
    const ushort8v u1 = *(const ushort8v*)(rowp + 8);
    float v[16];
#pragma unroll
    for (int j = 0; j < 8; ++j) { v[j] = bf2f(u0[j]); v[8 + j] = bf2f(u1[j]); }
    float s = 0.f, q = 0.f;
#pragma unroll
    for (int j = 0; j < 16; ++j) { s += v[j]; q += v[j] * v[j]; }
#pragma unroll
    for (int off = 1; off <= 32; off <<= 1) { s += __shfl_xor(s, off); q += __shfl_xor(q, off); }
    const float mean = s * (1.f / Dz);
    const float rstd = rsqrtf(q * (1.f / Dz) - mean * mean + EPSz);
#pragma unroll
    for (int j = 0; j < 16; ++j) acc[j] += (v[j] - mean) * rstd;
  }
  float* dst = pbuf + ((size_t)blockIdx.x * 4 + w) * Dz + l * 16;
#pragma unroll
  for (int j = 0; j < 4; ++j)
    *(float4*)(dst + j * 4) =
        make_float4(acc[j * 4], acc[j * 4 + 1], acc[j * 4 + 2], acc[j * 4 + 3]);
}

// ---------- K4c: emb[b] = invN * g * sum_{sub<32} pbuf[b*32+sub]
__global__ __launch_bounds__(256) void k_embred(
    const float* __restrict__ pbuf, const float* __restrict__ g,
    float* __restrict__ emb) {
  const int b = blockIdx.x, t = threadIdx.x;
  const float invN = 1.f / (float)Nz;
  const float* src = pbuf + (size_t)b * 32 * Dz + t * 4;
  float4 s = {0.f, 0.f, 0.f, 0.f};
#pragma unroll 8
  for (int sub = 0; sub < 32; ++sub) {
    const float4 v = *(const float4*)(src + (size_t)sub * Dz);
    s.x += v.x; s.y += v.y; s.z += v.z; s.w += v.w;
  }
  const float4 gv = *(const float4*)(g + t * 4);
  float4 o;
  o.x = s.x * gv.x * invN;
  o.y = s.y * gv.y * invN;
  o.z = s.z * gv.z * invN;
  o.w = s.w * gv.w * invN;
  *(float4*)(emb + (size_t)b * Dz + t * 4) = o;
}

// ---------- K5a: mid = gelu(emb @ W1 + b1)   grid (MID/64, B), K-split x4
__global__ __launch_bounds__(256) void k_mlp1(
    const float* __restrict__ emb, const float* __restrict__ W1,
    const float* __restrict__ b1, float* __restrict__ mid) {
  __shared__ float e[Dz];
  __shared__ float red[4][64];
  const int b = blockIdx.y, t = threadIdx.x;
  const int col0 = blockIdx.x * 64;
  *reinterpret_cast<float4*>(&e[t * 4]) =
      *reinterpret_cast<const float4*>(emb + (size_t)b * Dz + t * 4);
  __syncthreads();
  const int q = t >> 6, j = t & 63;
  float acc = 0.f;
  const float* W = W1 + (size_t)(q * 256) * MIDz + col0 + j;
#pragma unroll 8
  for (int k = 0; k < 256; ++k) acc += e[q * 256 + k] * W[(size_t)k * MIDz];
  red[q][j] = acc;
  __syncthreads();
  if (t < 64) {
    const float s = red[0][t] + red[1][t] + red[2][t] + red[3][t] + b1[col0 + t];
    mid[(size_t)b * MIDz + col0 + t] = 0.5f * s * (1.f + erff(s * 0.7071067811865475f));
  }
}

// ---------- K5b: pred = mid @ W2 + b2   grid (PROJ/64, B), K-split x4
__global__ __launch_bounds__(256) void k_mlp2(
    const float* __restrict__ mid, const float* __restrict__ W2,
    const float* __restrict__ b2, float* __restrict__ out) {
  __shared__ float e[MIDz];
  __shared__ float red[4][64];
  const int b = blockIdx.y, t = threadIdx.x;
  const int col0 = blockIdx.x * 64;
  if (t < MIDz / 4)
    *reinterpret_cast<float4*>(&e[t * 4]) =
        *reinterpret_cast<const float4*>(mid + (size_t)b * MIDz + t * 4);
  __syncthreads();
  const int q = t >> 6, j = t & 63;
  float acc = 0.f;
  const float* W = W2 + (size_t)(q * 192) * PROJz + col0 + j;
#pragma unroll 8
  for (int k = 0; k < 192; ++k) acc += e[q * 192 + k] * W[(size_t)k * PROJz];
  red[q][j] = acc;
  __syncthreads();
  if (t < 64)
    out[(size_t)b * PROJz + col0 + t] =
        red[0][t] + red[1][t] + red[2][t] + red[3][t] + b2[col0 + t];
}

extern "C" void kernel_launch(void* const* d_in, const int* in_sizes, int n_in,
                              void* d_out, int out_size, void* d_ws, size_t ws_size,
                              hipStream_t stream) {
  const float* x         = (const float*)d_in[0];
  const float* pos       = (const float*)d_in[1];
  const float* queries   = (const float*)d_in[2];
  const float* ln_q_g    = (const float*)d_in[3];
  const float* ln_ctx_g  = (const float*)d_in[4];
  const float* Wq        = (const float*)d_in[5];
  const float* Wkv       = (const float*)d_in[6];
  const float* Wout      = (const float*)d_in[7];
  const float* ln_post_g = (const float*)d_in[8];
  const float* W1        = (const float*)d_in[9];
  const float* b1        = (const float*)d_in[10];
  const float* W2        = (const float*)d_in[11];
  const float* b2        = (const float*)d_in[12];
  float* out = (float*)d_out;

  char* wsb = (char*)d_ws;
  float* emb   = (float*)wsb;                 // 131072 B
  float* mid   = (float*)(wsb + 131072);      // 98304 B
  u16*   WoutT = (u16*)(wsb + 229376);        // 1 MB
  u16*   aobf  = (u16*)(wsb + 1277952);       // 16.8 MB (dead after k_wgemm)
  float* pbuf  = (float*)(wsb + 1277952);     // 4 MB   (union w/ aobf)
  u16*   out1  = (u16*)(wsb + 18055168);      // 33.5 MB (union w/ below)
  u16*   WkvTg = (u16*)(wsb + 18055168);      // 256 KB
  u16*   WqTg  = (u16*)(wsb + 18317312);      // 1 MB
  float* cskv4 = (float*)(wsb + 19365888);    // 2 KB
  float* csq4  = (float*)(wsb + 19367936);    // 8 KB
  u16*   qbbf  = (u16*)(wsb + 19376128);      // 0.5 MB
  u16*   kbbf  = (u16*)(wsb + 19900416);      // 2 MB
  u16*   vTbf  = (u16*)(wsb + 21997568);      // 2 MB

  k_prepw<<<552, 256, 0, stream>>>(Wkv, Wq, ln_ctx_g, ln_q_g, WkvTg, WqTg, cskv4, csq4,
                                   Wout, WoutT);
  k_qproj<<<dim3(Nz / 16, 4), 256, 0, stream>>>(queries, WqTg, csq4, qbbf);
  k_ctxkv<<<(Bz * Nz) / 32, 256, 0, stream>>>(x, pos, WkvTg, cskv4, kbbf, vTbf);
  k_attn<<<dim3(Nz / 64, Hz / 2, Bz), 256, 0, stream>>>(qbbf, kbbf, vTbf, aobf);
  k_wgemm<<<dim3(Dz / 128, (Bz * Nz) / 128), 256, 0, stream>>>(aobf, WoutT, out1);
  k_lnmean<<<(Bz * Nz) / 64, 256, 0, stream>>>(out1, pbuf);
  k_embred<<<Bz, 256, 0, stream>>>(pbuf, ln_post_g, emb);
  k_mlp1<<<dim3(MIDz / 64, Bz), 256, 0, stream>>>(emb, W1, b1, mid);
  k_mlp2<<<dim3(PROJz / 64, Bz), 256, 0, stream>>>(mid, W2, b2, out);
}

// Round 18
// 157.495 us; speedup vs baseline: 1.2019x; 1.2019x over previous
//
#include <hip/hip_runtime.h>
#include <cmath>

#define Bz 32
#define Nz 512
#define Dz 1024
#define Hz 8
#define DHz 64
#define INNERz 512
#define PROJz 512
#define MIDz 768
#define EPSz 1e-5f

typedef unsigned short u16;
typedef unsigned int u32;
typedef __attribute__((ext_vector_type(8))) short short8v;
typedef __attribute__((ext_vector_type(8))) unsigned short ushort8v;
typedef __attribute__((ext_vector_type(4))) unsigned short ushort4v;
typedef __attribute__((ext_vector_type(4))) float f32x4;

__device__ __forceinline__ u16 f2bf(float x) {  // RNE f32 -> bf16 (finite inputs)
  unsigned u = __float_as_uint(x);
  unsigned r = u + 0x7fff + ((u >> 16) & 1);
  return (u16)(r >> 16);
}
__device__ __forceinline__ float bf2f(u16 u) {
  return __uint_as_float(((unsigned)u) << 16);
}
__device__ __forceinline__ float fexp2(float x) {  // 2^x, single v_exp_f32
  float r;
  asm("v_exp_f32 %0, %1" : "=v"(r) : "v"(x));
  return r;
}
__device__ __forceinline__ u32 cvtpk(float lo, float hi) {  // packed bf16(lo)|bf16(hi)<<16
  u32 r;
  asm("v_cvt_pk_bf16_f32 %0, %1, %2" : "=v"(r) : "v"(lo), "v"(hi));
  return r;
}

// ---------- P0: weight prep. blocks 0..39: WkvTg/WqTg + colsums. blocks 40..551: Wout^T.
__global__ __launch_bounds__(256) void k_prepw(
    const float* __restrict__ Wkv, const float* __restrict__ Wq,
    const float* __restrict__ g_ctx, const float* __restrict__ g_q,
    u16* __restrict__ WkvTg, u16* __restrict__ WqTg,
    float* __restrict__ cskv4, float* __restrict__ csq4,
    const float* __restrict__ Wout, u16* __restrict__ WoutT) {
  __shared__ float part[64][4];
  __shared__ float sm[32][33];
  const int t = threadIdx.x;
  const int blk = blockIdx.x;
  if (blk >= 40) {  // Wout transpose: WoutT[n][k] = bf16(Wout[k][n])
    const int bid2 = blk - 40;
    const int n0 = (bid2 & 31) * 32, k0 = (bid2 >> 5) * 32;
    {
      const int kk = t >> 3, nn = (t & 7) * 4;
      const float4 v = *reinterpret_cast<const float4*>(Wout + (size_t)(k0 + kk) * Dz + n0 + nn);
      sm[kk][nn] = v.x; sm[kk][nn + 1] = v.y; sm[kk][nn + 2] = v.z; sm[kk][nn + 3] = v.w;
    }
    __syncthreads();
    const int nn = t >> 3, kk = (t & 7) * 4;
    ushort4v pk;
#pragma unroll
    for (int j = 0; j < 4; ++j) pk[j] = f2bf(sm[kk + j][nn]);
    *reinterpret_cast<ushort4v*>(WoutT + (size_t)(n0 + nn) * INNERz + k0 + kk) = pk;
    return;
  }
  const int jg = blk >> 2, quarter = blk & 3;
  const bool isq = jg >= 2;
  const int jbase = isq ? (jg - 2) * 64 : jg * 64;
  const int j = jbase + (t & 63);
  const int dsub = t >> 6;
  const float* W = isq ? Wq : Wkv;
  const int ld = isq ? 512 : 128;
  const float* g = isq ? g_q : g_ctx;
  const float scale = isq ? 0.125f * 1.4426950408889634f : 1.f;  // fold DH^-0.5 * log2e
  u16* WT = isq ? WqTg : WkvTg;
  float partial = 0.f;
  const int d0beg = quarter * 256 + dsub * 64;
  for (int d0 = d0beg; d0 < d0beg + 64; d0 += 2) {
    const float v0 = scale * g[d0] * W[(size_t)d0 * ld + j];
    const float v1 = scale * g[d0 + 1] * W[(size_t)(d0 + 1) * ld + j];
    partial += v0 + v1;
    *(u32*)(WT + (size_t)j * Dz + d0) = (u32)f2bf(v0) | ((u32)f2bf(v1) << 16);
  }
  part[t & 63][dsub] = partial;
  __syncthreads();
  if (t < 64)
    (isq ? csq4 : cskv4)[(jbase + t) * 4 + quarter] =
        part[t][0] + part[t][1] + part[t][2] + part[t][3];
}

#define LOADB2(dst, kk)                                                        \
  {                                                                            \
    _Pragma("unroll") for (int u_ = 0; u_ < 4; ++u_)                           \
    _Pragma("unroll") for (int cf_ = 0; cf_ < 2; ++cf_)                        \
        dst[u_][cf_] =                                                         \
            *(const short8v*)(Bp + (size_t)cf_ * 16 * Dz + (kk) + u_ * 32);    \
  }

// ---------- P1: qb = bf16( LN(queries)*g @ Wq * 0.125*log2e )  (reg-pipelined MFMA)
__global__ __launch_bounds__(256) void k_qproj(
    const float* __restrict__ queries, const u16* __restrict__ WT,
    const float* __restrict__ cs4, u16* __restrict__ qbuf) {
  __shared__ u16 hbuf[16 * 1024];
  __shared__ float mm[16], rr[16];
  char* hb = (char*)hbuf;
  const int t = threadIdx.x;
  const int w = t >> 6, l = t & 63;
  const int lr = l & 15, lk = l >> 4;
  const int c0 = blockIdx.y * 128 + w * 32;
  const u16* Bp = WT + (size_t)(c0 + lr) * Dz + lk * 8;
  short8v bcur[4][2], bnxt[4][2];
  LOADB2(bcur, 0);
  {
    const int r = t >> 4, c16 = t & 15;
    const long grow = (long)blockIdx.x * 16 + r;
    const float* xr = queries + grow * Dz;
    float s = 0.f, ss = 0.f;
    const int swz = (r & 7) << 4;
#pragma unroll
    for (int i = 0; i < 16; ++i) {
      const int col = c16 * 4 + i * 64;
      const float4 v = *(const float4*)(xr + col);
      s += (v.x + v.y) + (v.z + v.w);
      ss += (v.x * v.x + v.y * v.y) + (v.z * v.z + v.w * v.w);
      uint2 pk;
      pk.x = (u32)f2bf(v.x) | ((u32)f2bf(v.y) << 16);
      pk.y = (u32)f2bf(v.z) | ((u32)f2bf(v.w) << 16);
      *(uint2*)(hb + ((r * 2048 + col * 2) ^ swz)) = pk;
    }
#pragma unroll
    for (int off = 1; off <= 8; off <<= 1) { s += __shfl_xor(s, off); ss += __shfl_xor(ss, off); }
    const float mean = s * (1.f / Dz);
    const float rstd = rsqrtf(ss * (1.f / Dz) - mean * mean + EPSz);
    if (c16 == 0) { mm[r] = mean; rr[r] = rstd; }
  }
  __syncthreads();
  f32x4 acc[2];
  acc[0] = {0.f, 0.f, 0.f, 0.f};
  acc[1] = {0.f, 0.f, 0.f, 0.f};
  const int aswz = (lr & 7) << 4;
#pragma unroll
  for (int k0 = 0; k0 < Dz; k0 += 128) {
    if (k0 + 128 < Dz) LOADB2(bnxt, k0 + 128);
#pragma unroll
    for (int u = 0; u < 4; ++u) {
      const int kk = (k0 + u * 32 + lk * 8) * 2;
      const short8v a = *(const short8v*)(hb + ((lr * 2048 + kk) ^ aswz));
      acc[0] = __builtin_amdgcn_mfma_f32_16x16x32_bf16(a, bcur[u][0], acc[0], 0, 0, 0);
      acc[1] = __builtin_amdgcn_mfma_f32_16x16x32_bf16(a, bcur[u][1], acc[1], 0, 0, 0);
    }
    if (k0 + 128 < Dz) {
#pragma unroll
      for (int u = 0; u < 4; ++u) {
        bcur[u][0] = bnxt[u][0];
        bcur[u][1] = bnxt[u][1];
      }
    }
  }
  const long base = (long)blockIdx.x * 16;
#pragma unroll
  for (int cf = 0; cf < 2; ++cf) {
    const int col = c0 + cf * 16 + lr;
    const float c = cs4[col * 4] + cs4[col * 4 + 1] + cs4[col * 4 + 2] + cs4[col * 4 + 3];
#pragma unroll
    for (int q = 0; q < 4; ++q) {
      const int row = lk * 4 + q;
      qbuf[(size_t)(base + row) * INNERz + col] = f2bf(rr[row] * (acc[cf][q] - mm[row] * c));
    }
  }
}

// ---------- P2: k,v = LN(x+pos)*g @ Wkv  (32 rows/block; batched staging loads)
__global__ __launch_bounds__(256, 2) void k_ctxkv(
    const float* __restrict__ x, const float* __restrict__ pos,
    const u16* __restrict__ WT, const float* __restrict__ cs4,
    u16* __restrict__ kb, u16* __restrict__ vT) {
  __shared__ u16 hbuf[32 * 1024];   // 64 KB
  __shared__ float mm[32], rrs[32];
  char* hb = (char*)hbuf;
  const int t = threadIdx.x;
  const int w = t >> 6, l = t & 63;
  const int lr = l & 15, lk = l >> 4;
  const int c0 = w * 32;
  const u16* Bp = WT + (size_t)(c0 + lr) * Dz + lk * 8;
  short8v bcur[4][2], bnxt[4][2];
  LOADB2(bcur, 0);
  {
    const int r2 = t >> 4, c16 = t & 15;
#pragma unroll
    for (int half = 0; half < 2; ++half) {
      const int r = r2 + half * 16;
      const long grow = (long)blockIdx.x * 32 + r;
      const int n = (int)(grow & (Nz - 1));
      const float* xr = x + grow * Dz;
      const float* pr = pos + (size_t)n * Dz;
      float s = 0.f, ss = 0.f;
      const int swz = (r & 7) << 4;
#pragma unroll
      for (int bat = 0; bat < 2; ++bat) {
        float4 xv[8], pv[8];
#pragma unroll
        for (int i = 0; i < 8; ++i) {
          const int col = c16 * 4 + (bat * 8 + i) * 64;
          xv[i] = *(const float4*)(xr + col);
          pv[i] = *(const float4*)(pr + col);
        }
#pragma unroll
        for (int i = 0; i < 8; ++i) {
          const int col = c16 * 4 + (bat * 8 + i) * 64;
          float4 v = xv[i];
          const float4 p = pv[i];
          v.x += p.x; v.y += p.y; v.z += p.z; v.w += p.w;
          s += (v.x + v.y) + (v.z + v.w);
          ss += (v.x * v.x + v.y * v.y) + (v.z * v.z + v.w * v.w);
          uint2 pk;
          pk.x = (u32)f2bf(v.x) | ((u32)f2bf(v.y) << 16);
          pk.y = (u32)f2bf(v.z) | ((u32)f2bf(v.w) << 16);
          *(uint2*)(hb + ((r * 2048 + col * 2) ^ swz)) = pk;
        }
      }
#pragma unroll
      for (int off = 1; off <= 8; off <<= 1) { s += __shfl_xor(s, off); ss += __shfl_xor(ss, off); }
      const float mean = s * (1.f / Dz);
      const float rstd = rsqrtf(ss * (1.f / Dz) - mean * mean + EPSz);
      if (c16 == 0) { mm[r] = mean; rrs[r] = rstd; }
    }
  }
  __syncthreads();
  f32x4 acc[2][2];  // [row-frag][col-frag]
#pragma unroll
  for (int rf = 0; rf < 2; ++rf)
#pragma unroll
    for (int cf = 0; cf < 2; ++cf) acc[rf][cf] = {0.f, 0.f, 0.f, 0.f};
  const int aswz = (lr & 7) << 4;
#pragma unroll
  for (int k0 = 0; k0 < Dz; k0 += 128) {
    if (k0 + 128 < Dz) LOADB2(bnxt, k0 + 128);
#pragma unroll
    for (int u = 0; u < 4; ++u) {
      const int kk = (k0 + u * 32 + lk * 8) * 2;
      const short8v a0 = *(const short8v*)(hb + ((lr * 2048 + kk) ^ aswz));
      const short8v a1 = *(const short8v*)(hb + (((lr + 16) * 2048 + kk) ^ aswz));
      acc[0][0] = __builtin_amdgcn_mfma_f32_16x16x32_bf16(a0, bcur[u][0], acc[0][0], 0, 0, 0);
      acc[0][1] = __builtin_amdgcn_mfma_f32_16x16x32_bf16(a0, bcur[u][1], acc[0][1], 0, 0, 0);
      acc[1][0] = __builtin_amdgcn_mfma_f32_16x16x32_bf16(a1, bcur[u][0], acc[1][0], 0, 0, 0);
      acc[1][1] = __builtin_amdgcn_mfma_f32_16x16x32_bf16(a1, bcur[u][1], acc[1][1], 0, 0, 0);
    }
    if (k0 + 128 < Dz) {
#pragma unroll
      for (int u = 0; u < 4; ++u) {
        bcur[u][0] = bnxt[u][0];
        bcur[u][1] = bnxt[u][1];
      }
    }
  }
  const long base = (long)blockIdx.x * 32;
  const int bb = (int)(base >> 9), nb0 = (int)(base & (Nz - 1));
#pragma unroll
  for (int rf = 0; rf < 2; ++rf)
#pragma unroll
    for (int cf = 0; cf < 2; ++cf) {
      const int col = c0 + cf * 16 + lr;
      const float c = cs4[col * 4] + cs4[col * 4 + 1] + cs4[col * 4 + 2] + cs4[col * 4 + 3];
      if (col < 64) {
#pragma unroll
        for (int q = 0; q < 4; ++q) {
          const int row = rf * 16 + lk * 4 + q;
          kb[(size_t)(base + row) * DHz + col] = f2bf(rrs[row] * (acc[rf][cf][q] - mm[row] * c));
        }
      } else {
        ushort4v pk;
#pragma unroll
        for (int q = 0; q < 4; ++q) {
          const int row = rf * 16 + lk * 4 + q;
          pk[q] = f2bf(rrs[row] * (acc[rf][cf][q] - mm[row] * c));
        }
        *(ushort4v*)(vT + ((size_t)bb * DHz + (col - 64)) * Nz + nb0 + rf * 16 + lk * 4) = pk;
      }
    }
}

// ---------- K3: MFMA flash attention. 4 waves/256 thr; 2 heads per wave; K/V staged 4x.
__global__ __launch_bounds__(256) void k_attn(
    const u16* __restrict__ qb, const u16* __restrict__ kb,
    const u16* __restrict__ vT, u16* __restrict__ ao) {
  __shared__ u16 Ks[2][4096];
  __shared__ u16 Vs[2][4096];
  __shared__ u16 plds[4][2048];   // per wave: 2 heads x (16x64) bf16
  const int t = threadIdx.x;
  const int w = t >> 6, l = t & 63;
  const int lr = l & 15, lk = l >> 4;
  const int m0 = blockIdx.x * 64 + w * 16;
  const int h0 = blockIdx.y * 2;
  const int b = blockIdx.z;
  const u16* qr = qb + (size_t)(m0 + lr) * INNERz + h0 * DHz + lk * 8;
  const short8v aq00 = *(const short8v*)qr;
  const short8v aq01 = *(const short8v*)(qr + 32);
  const short8v aq10 = *(const short8v*)(qr + 64);
  const short8v aq11 = *(const short8v*)(qr + 96);
  const u16* kbB = kb + (size_t)b * Nz * DHz;
  const u16* vTB = vT + (size_t)b * DHz * Nz;
  char* pw0 = (char*)&plds[w][0];
  char* pw1 = (char*)&plds[w][1024];
  const int swz = (lr & 7) << 4;

  const int srow = w * 16 + (l >> 3);
  const int schunk = (l & 7) ^ (l >> 3);

#define STAGE(bufi, j0v)                                                              \
  {                                                                                   \
    _Pragma("unroll") for (int c = 0; c < 2; ++c) {                                   \
      __builtin_amdgcn_global_load_lds(                                               \
          (const __attribute__((address_space(1))) u32*)(const void*)(                \
              kbB + (size_t)((j0v) + srow + c * 8) * DHz + schunk * 8),               \
          (__attribute__((address_space(3))) u32*)(void*)(&Ks[bufi][0] + w * 1024 + c * 512), \
          16, 0, 0);                                                                  \
      __builtin_amdgcn_global_load_lds(                                               \
          (const __attribute__((address_space(1))) u32*)(const void*)(                \
              vTB + (size_t)(srow + c * 8) * Nz + (j0v) + schunk * 8),                \
          (__attribute__((address_space(3))) u32*)(void*)(&Vs[bufi][0] + w * 1024 + c * 512), \
          16, 0, 0);                                                                  \
    }                                                                                 \
  }

  f32x4 oacc0[4], oacc1[4];
#pragma unroll
  for (int dn = 0; dn < 4; ++dn) { oacc0[dn] = {0.f, 0.f, 0.f, 0.f}; oacc1[dn] = {0.f, 0.f, 0.f, 0.f}; }
  float lsum0 = 0.f, lsum1 = 0.f;

  int buf = 0;
  STAGE(0, 0);
  asm volatile("s_waitcnt vmcnt(0)" ::: "memory");
  __builtin_amdgcn_s_barrier();
  asm volatile("" ::: "memory");

  for (int tt = 0; tt < 8; ++tt) {
    if (tt < 7) STAGE(buf ^ 1, (tt + 1) * 64);
    asm volatile("" ::: "memory");
    const char* Kb = (const char*)&Ks[buf][0];
    const char* Vb = (const char*)&Vs[buf][0];
    {
      f32x4 sfr[4];
#pragma unroll
      for (int jn = 0; jn < 4; ++jn) {
        const int rbase = jn * 2048 + lr * 128;
        const short8v bk0 = *(const short8v*)(Kb + rbase + ((lk * 16) ^ swz));
        const short8v bk1 = *(const short8v*)(Kb + rbase + ((64 + lk * 16) ^ swz));
        f32x4 c = {0.f, 0.f, 0.f, 0.f};
        c = __builtin_amdgcn_mfma_f32_16x16x32_bf16(bk0, aq00, c, 0, 0, 0);
        c = __builtin_amdgcn_mfma_f32_16x16x32_bf16(bk1, aq01, c, 0, 0, 0);
        sfr[jn] = c;
      }
      float ps = 0.f;
#pragma unroll
      for (int jn = 0; jn < 4; ++jn) {
        const float e0 = fexp2(sfr[jn][0]);
        const float e1 = fexp2(sfr[jn][1]);
        const float e2 = fexp2(sfr[jn][2]);
        const float e3 = fexp2(sfr[jn][3]);
        ps += (e0 + e1) + (e2 + e3);
        const int pbase = (lr * 128 + jn * 32 + lk * 8) ^ swz;
        *(u32*)(pw0 + pbase) = cvtpk(e0, e1);
        *(u32*)(pw0 + pbase + 4) = cvtpk(e2, e3);
      }
      lsum0 += ps;
    }
    {
      f32x4 sfr[4];
#pragma unroll
      for (int jn = 0; jn < 4; ++jn) {
        const int rbase = jn * 2048 + lr * 128;
        const short8v bk0 = *(const short8v*)(Kb + rbase + ((lk * 16) ^ swz));
        const short8v bk1 = *(const short8v*)(Kb + rbase + ((64 + lk * 16) ^ swz));
        f32x4 c = {0.f, 0.f, 0.f, 0.f};
        c = __builtin_amdgcn_mfma_f32_16x16x32_bf16(bk0, aq10, c, 0, 0, 0);
        c = __builtin_amdgcn_mfma_f32_16x16x32_bf16(bk1, aq11, c, 0, 0, 0);
        sfr[jn] = c;
      }
      float ps = 0.f;
#pragma unroll
      for (int jn = 0; jn < 4; ++jn) {
        const float e0 = fexp2(sfr[jn][0]);
        const float e1 = fexp2(sfr[jn][1]);
        const float e2 = fexp2(sfr[jn][2]);
        const float e3 = fexp2(sfr[jn][3]);
        ps += (e0 + e1) + (e2 + e3);
        const int pbase = (lr * 128 + jn * 32 + lk * 8) ^ swz;
        *(u32*)(pw1 + pbase) = cvtpk(e0, e1);
        *(u32*)(pw1 + pbase + 4) = cvtpk(e2, e3);
      }
      lsum1 += ps;
    }
    const short8v pa00 = *(const short8v*)(pw0 + ((lr * 128 + lk * 16) ^ swz));
    const short8v pa01 = *(const short8v*)(pw0 + ((lr * 128 + 64 + lk * 16) ^ swz));
    const short8v pa10 = *(const short8v*)(pw1 + ((lr * 128 + lk * 16) ^ swz));
    const short8v pa11 = *(const short8v*)(pw1 + ((lr * 128 + 64 + lk * 16) ^ swz));
#pragma unroll
    for (int dn = 0; dn < 4; ++dn) {
      const int rbase = dn * 2048 + lr * 128;
      const short8v bv0 = *(const short8v*)(Vb + rbase + ((lk * 16) ^ swz));
      const short8v bv1 = *(const short8v*)(Vb + rbase + ((64 + lk * 16) ^ swz));
      f32x4 o0 = oacc0[dn];
      o0 = __builtin_amdgcn_mfma_f32_16x16x32_bf16(pa00, bv0, o0, 0, 0, 0);
      o0 = __builtin_amdgcn_mfma_f32_16x16x32_bf16(pa01, bv1, o0, 0, 0, 0);
      oacc0[dn] = o0;
      f32x4 o1 = oacc1[dn];
      o1 = __builtin_amdgcn_mfma_f32_16x16x32_bf16(pa10, bv0, o1, 0, 0, 0);
      o1 = __builtin_amdgcn_mfma_f32_16x16x32_bf16(pa11, bv1, o1, 0, 0, 0);
      oacc1[dn] = o1;
    }
    asm volatile("" ::: "memory");
    if (tt < 7) asm volatile("s_waitcnt vmcnt(0)" ::: "memory");
    __builtin_amdgcn_s_barrier();
    asm volatile("" ::: "memory");
    buf ^= 1;
  }
#undef STAGE
  lsum0 += __shfl_xor(lsum0, 16);
  lsum0 += __shfl_xor(lsum0, 32);
  lsum1 += __shfl_xor(lsum1, 16);
  lsum1 += __shfl_xor(lsum1, 32);
  float rinv0[4], rinv1[4];
#pragma unroll
  for (int r = 0; r < 4; ++r) {
    rinv0[r] = 1.f / __shfl(lsum0, lk * 4 + r, 64);
    rinv1[r] = 1.f / __shfl(lsum1, lk * 4 + r, 64);
  }
#pragma unroll
  for (int dn = 0; dn < 4; ++dn)
#pragma unroll
    for (int r = 0; r < 4; ++r) {
      const int row = m0 + lk * 4 + r;
      const size_t rbase = ((size_t)b * Nz + row) * INNERz;
      ao[rbase + h0 * DHz + dn * 16 + lr] = f2bf(oacc0[dn][r] * rinv0[r]);
      ao[rbase + (h0 + 1) * DHz + dn * 16 + lr] = f2bf(oacc1[dn][r] * rinv1[r]);
    }
}

// ---------- K4a: out1 = bf16( ao @ Wout )  (128x128 tile, BK=64, XCD-swizzled grid)
__global__ __launch_bounds__(256) void k_wgemm(
    const u16* __restrict__ A, const u16* __restrict__ BT, u16* __restrict__ C) {
  __shared__ u16 As[128 * 64];
  __shared__ u16 Bs[128 * 64];
  const int t = threadIdx.x;
  const int w = t >> 6, l = t & 63;
  const int lin = blockIdx.y * gridDim.x + blockIdx.x;
  const int swzl = (lin & 7) * 128 + (lin >> 3);
  const int m0 = (swzl >> 3) * 128, n0 = (swzl & 7) * 128;
  const int wr = w >> 1, wc = w & 1;
  const int lr = l & 15, lk = l >> 4;

  f32x4 acc[4][4];
#pragma unroll
  for (int mt = 0; mt < 4; ++mt)
#pragma unroll
    for (int nt = 0; nt < 4; ++nt) acc[mt][nt] = {0.f, 0.f, 0.f, 0.f};

  for (int k0 = 0; k0 < INNERz; k0 += 64) {
#pragma unroll
    for (int c = 0; c < 4; ++c) {
      const int rowblk = w * 32 + c * 8;
      const int row = rowblk + (l >> 3);
      const int kb16 = (l & 7) * 8;
      __builtin_amdgcn_global_load_lds(
          (const __attribute__((address_space(1))) unsigned int*)(const void*)(
              A + (size_t)(m0 + row) * INNERz + k0 + kb16),
          (__attribute__((address_space(3))) unsigned int*)(void*)(As + rowblk * 64),
          16, 0, 0);
      __builtin_amdgcn_global_load_lds(
          (const __attribute__((address_space(1))) unsigned int*)(const void*)(
              BT + (size_t)(n0 + row) * INNERz + k0 + kb16),
          (__attribute__((address_space(3))) unsigned int*)(void*)(Bs + rowblk * 64),
          16, 0, 0);
    }
    __syncthreads();
#pragma unroll
    for (int ks = 0; ks < 2; ++ks) {
      short8v af[4], bf[4];
#pragma unroll
      for (int mt = 0; mt < 4; ++mt)
        af[mt] = *reinterpret_cast<const short8v*>(As + (wr * 64 + mt * 16 + lr) * 64 + ks * 32 + lk * 8);
#pragma unroll
      for (int nt = 0; nt < 4; ++nt)
        bf[nt] = *reinterpret_cast<const short8v*>(Bs + (wc * 64 + nt * 16 + lr) * 64 + ks * 32 + lk * 8);
#pragma unroll
      for (int mt = 0; mt < 4; ++mt)
#pragma unroll
        for (int nt = 0; nt < 4; ++nt)
          acc[mt][nt] = __builtin_amdgcn_mfma_f32_16x16x32_bf16(af[mt], bf[nt], acc[mt][nt], 0, 0, 0);
    }
    __syncthreads();
  }
#pragma unroll
  for (int mt = 0; mt < 4; ++mt)
#pragma unroll
    for (int nt = 0; nt < 4; ++nt) {
      const f32x4 a = acc[mt][nt];
#pragma unroll
      for (int r = 0; r < 4; ++r) {
        const size_t row = (size_t)m0 + wr * 64 + mt * 16 + lk * 4 + r;
        C[row * Dz + n0 + wc * 64 + nt * 16 + lr] = f2bf(a[r]);
      }
    }
}

// ---------- K4b: per-wave LN partial sums, 16 vals/lane, no spill, no atomics
__global__ __launch_bounds__(256) void k_lnmean(
    const u16* __restrict__ out1, float* __restrict__ pbuf) {
  const int t = threadIdx.x;
  const int w = t >> 6, l = t & 63;
  const long row0 = (long)blockIdx.x * 64 + w * 16;
  float acc[16];
#pragma unroll
  for (int j = 0; j < 16; ++j) acc[j] = 0.f;
  for (int rr = 0; rr < 16; ++rr) {
    const u16* rowp = out1 + (size_t)(row0 + rr) * Dz + l * 16;
    const ushort8v u0 = *(const ushort8v*)(rowp);
    const ushort8v u1 = *(const ushort8v*)(rowp + 8);
    float v[16];
#pragma unroll
    for (int j = 0; j < 8; ++j) { v[j] = bf2f(u0[j]); v[8 + j] = bf2f(u1[j]); }
    float s = 0.f, q = 0.f;
#pragma unroll
    for (int j = 0; j < 16; ++j) { s += v[j]; q += v[j] * v[j]; }
#pragma unroll
    for (int off = 1; off <= 32; off <<= 1) { s += __shfl_xor(s, off); q += __shfl_xor(q, off); }
    const float mean = s * (1.f / Dz);
    const float rstd = rsqrtf(q * (1.f / Dz) - mean * mean + EPSz);
#pragma unroll
    for (int j = 0; j < 16; ++j) acc[j] += (v[j] - mean) * rstd;
  }
  float* dst = pbuf + ((size_t)blockIdx.x * 4 + w) * Dz + l * 16;
#pragma unroll
  for (int j = 0; j < 4; ++j)
    *(float4*)(dst + j * 4) =
        make_float4(acc[j * 4], acc[j * 4 + 1], acc[j * 4 + 2], acc[j * 4 + 3]);
}

// ---------- K4c: emb[b] = invN * g * sum_{sub<32} pbuf[b*32+sub]
__global__ __launch_bounds__(256) void k_embred(
    const float* __restrict__ pbuf, const float* __restrict__ g,
    float* __restrict__ emb) {
  const int b = blockIdx.x, t = threadIdx.x;
  const float invN = 1.f / (float)Nz;
  const float* src = pbuf + (size_t)b * 32 * Dz + t * 4;
  float4 s = {0.f, 0.f, 0.f, 0.f};
#pragma unroll 8
  for (int sub = 0; sub < 32; ++sub) {
    const float4 v = *(const float4*)(src + (size_t)sub * Dz);
    s.x += v.x; s.y += v.y; s.z += v.z; s.w += v.w;
  }
  const float4 gv = *(const float4*)(g + t * 4);
  float4 o;
  o.x = s.x * gv.x * invN;
  o.y = s.y * gv.y * invN;
  o.z = s.z * gv.z * invN;
  o.w = s.w * gv.w * invN;
  *(float4*)(emb + (size_t)b * Dz + t * 4) = o;
}

// ---------- K5a: mid = gelu(emb @ W1 + b1)   grid (MID/64, B), K-split x4
__global__ __launch_bounds__(256) void k_mlp1(
    const float* __restrict__ emb, const float* __restrict__ W1,
    const float* __restrict__ b1, float* __restrict__ mid) {
  __shared__ float e[Dz];
  __shared__ float red[4][64];
  const int b = blockIdx.y, t = threadIdx.x;
  const int col0 = blockIdx.x * 64;
  *reinterpret_cast<float4*>(&e[t * 4]) =
      *reinterpret_cast<const float4*>(emb + (size_t)b * Dz + t * 4);
  __syncthreads();
  const int q = t >> 6, j = t & 63;
  float acc = 0.f;
  const float* W = W1 + (size_t)(q * 256) * MIDz + col0 + j;
#pragma unroll 8
  for (int k = 0; k < 256; ++k) acc += e[q * 256 + k] * W[(size_t)k * MIDz];
  red[q][j] = acc;
  __syncthreads();
  if (t < 64) {
    const float s = red[0][t] + red[1][t] + red[2][t] + red[3][t] + b1[col0 + t];
    mid[(size_t)b * MIDz + col0 + t] = 0.5f * s * (1.f + erff(s * 0.7071067811865475f));
  }
}

// ---------- K5b: pred = mid @ W2 + b2   grid (PROJ/64, B), K-split x4
__global__ __launch_bounds__(256) void k_mlp2(
    const float* __restrict__ mid, const float* __restrict__ W2,
    const float* __restrict__ b2, float* __restrict__ out) {
  __shared__ float e[MIDz];
  __shared__ float red[4][64];
  const int b = blockIdx.y, t = threadIdx.x;
  const int col0 = blockIdx.x * 64;
  if (t < MIDz / 4)
    *reinterpret_cast<float4*>(&e[t * 4]) =
        *reinterpret_cast<const float4*>(mid + (size_t)b * MIDz + t * 4);
  __syncthreads();
  const int q = t >> 6, j = t & 63;
  float acc = 0.f;
  const float* W = W2 + (size_t)(q * 192) * PROJz + col0 + j;
#pragma unroll 8
  for (int k = 0; k < 192; ++k) acc += e[q * 192 + k] * W[(size_t)k * PROJz];
  red[q][j] = acc;
  __syncthreads();
  if (t < 64)
    out[(size_t)b * PROJz + col0 + t] =
        red[0][t] + red[1][t] + red[2][t] + red[3][t] + b2[col0 + t];
}

extern "C" void kernel_launch(void* const* d_in, const int* in_sizes, int n_in,
                              void* d_out, int out_size, void* d_ws, size_t ws_size,
                              hipStream_t stream) {
  const float* x         = (const float*)d_in[0];
  const float* pos       = (const float*)d_in[1];
  const float* queries   = (const float*)d_in[2];
  const float* ln_q_g    = (const float*)d_in[3];
  const float* ln_ctx_g  = (const float*)d_in[4];
  const float* Wq        = (const float*)d_in[5];
  const float* Wkv       = (const float*)d_in[6];
  const float* Wout      = (const float*)d_in[7];
  const float* ln_post_g = (const float*)d_in[8];
  const float* W1        = (const float*)d_in[9];
  const float* b1        = (const float*)d_in[10];
  const float* W2        = (const float*)d_in[11];
  const float* b2        = (const float*)d_in[12];
  float* out = (float*)d_out;

  char* wsb = (char*)d_ws;
  float* emb   = (float*)wsb;                 // 131072 B
  float* mid   = (float*)(wsb + 131072);      // 98304 B
  u16*   WoutT = (u16*)(wsb + 229376);        // 1 MB
  u16*   aobf  = (u16*)(wsb + 1277952);       // 16.8 MB (dead after k_wgemm)
  float* pbuf  = (float*)(wsb + 1277952);     // 4 MB   (union w/ aobf)
  u16*   out1  = (u16*)(wsb + 18055168);      // 33.5 MB (union w/ below)
  u16*   WkvTg = (u16*)(wsb + 18055168);      // 256 KB
  u16*   WqTg  = (u16*)(wsb + 18317312);      // 1 MB
  float* cskv4 = (float*)(wsb + 19365888);    // 2 KB
  float* csq4  = (float*)(wsb + 19367936);    // 8 KB
  u16*   qbbf  = (u16*)(wsb + 19376128);      // 0.5 MB
  u16*   kbbf  = (u16*)(wsb + 19900416);      // 2 MB
  u16*   vTbf  = (u16*)(wsb + 21997568);      // 2 MB

  k_prepw<<<552, 256, 0, stream>>>(Wkv, Wq, ln_ctx_g, ln_q_g, WkvTg, WqTg, cskv4, csq4,
                                   Wout, WoutT);
  k_qproj<<<dim3(Nz / 16, 4), 256, 0, stream>>>(queries, WqTg, csq4, qbbf);
  k_ctxkv<<<(Bz * Nz) / 32, 256, 0, stream>>>(x, pos, WkvTg, cskv4, kbbf, vTbf);
  k_attn<<<dim3(Nz / 64, Hz / 2, Bz), 256, 0, stream>>>(qbbf, kbbf, vTbf, aobf);
  k_wgemm<<<dim3(Dz / 128, (Bz * Nz) / 128), 256, 0, stream>>>(aobf, WoutT, out1);
  k_lnmean<<<(Bz * Nz) / 64, 256, 0, stream>>>(out1, pbuf);
  k_embred<<<Bz, 256, 0, stream>>>(pbuf, ln_post_g, emb);
  k_mlp1<<<dim3(MIDz / 64, Bz), 256, 0, stream>>>(emb, W1, b1, mid);
  k_mlp2<<<dim3(PROJz / 64, Bz), 256, 0, stream>>>(mid, W2, b2, out);
}